// Round 12
// baseline (5472.330 us; speedup 1.0000x reference)
//
#include <hip/hip_runtime.h>

#define DEVI __device__ __forceinline__

typedef __attribute__((ext_vector_type(8))) __bf16 bf16x8;
typedef __attribute__((ext_vector_type(4))) float floatx4;

constexpr int Bsz = 8192;   // batch
constexpr int Hd  = 2048;   // hidden
constexpr int INd = 2048;   // input dim
constexpr int N1  = Bsz * INd;

DEVI unsigned short f2bf_rne(float f) {
  unsigned int u = __float_as_uint(f);
  u += 0x7FFFu + ((u >> 16) & 1u);
  return (unsigned short)(u >> 16);
}

__global__ void cvt4(const float* __restrict__ s0, const float* __restrict__ s1,
                     const float* __restrict__ s2, const float* __restrict__ s3,
                     unsigned short* __restrict__ dst) {
  const float* src = (blockIdx.y == 0) ? s0 : (blockIdx.y == 1) ? s1
                   : (blockIdx.y == 2) ? s2 : s3;
  unsigned short* out = dst + (size_t)blockIdx.y * N1;
  const int nv = N1 / 4;
  for (int i = blockIdx.x * blockDim.x + threadIdx.x; i < nv;
       i += gridDim.x * blockDim.x) {
    float4 v = ((const float4*)src)[i];
    ushort4 o;
    o.x = f2bf_rne(v.x); o.y = f2bf_rne(v.y);
    o.z = f2bf_rne(v.z); o.w = f2bf_rne(v.w);
    ((ushort4*)out)[i] = o;
  }
}

DEVI void gload_lds16(const void* g, void* l) {
  __builtin_amdgcn_global_load_lds(
      (const __attribute__((address_space(1))) void*)g,
      (__attribute__((address_space(3))) void*)l, 16, 0, 0);
}

DEVI float sigm(float x) { return 1.0f / (1.0f + __expf(-x)); }
DEVI float tanh_fast(float x) { return 1.0f - 2.0f / (1.0f + __expf(2.0f * x)); }

// R12: 256x256 tile, BK=32, 8 waves (2M x 4N), 16x16x32 MFMA.
// LDS = 2buf x (A[256][32] + B[256][32]) bf16 = 64 KiB -> 2 BLOCKS/CU
// (4 waves/SIMD): cross-block TLP covers barriers/waits that R6-R10 schedule
// surgery could not (1 block = 2 waves/SIMD left the SIMD idle at each sync).
// 12 ds_read_b128/wave/K-tile (unique min), precomputed bases + compile-time
// offsets (R11's +7pp win), 4-chunk swizzle phys = lk ^ ((lr>>1)&3):
// per 16B chunk-slot exactly 8 lanes = 32 B/bank = the b128 minimum -> 0
// extra conflicts. Staging pre-swizzles the global source (rule #21).
// Depth-1 staging: tile t stages t+1 (4 gloads), counted drain at ph4.
__global__ __launch_bounds__(512, 4) void lstm_gemm(
    const unsigned short* __restrict__ ws,
    const float* __restrict__ bias,
    const float* __restrict__ c_prev,
    float* __restrict__ out_h,
    float* __restrict__ out_c) {
  __shared__ __align__(16) unsigned short sm[2 * 2 * 256 * 32];  // 64 KiB
  char* smc = (char*)sm;

  const unsigned short* xb  = ws;
  const unsigned short* hb  = ws + (size_t)N1;
  const unsigned short* wih = ws + (size_t)2 * N1;
  const unsigned short* whh = ws + (size_t)3 * N1;

  const int tid  = threadIdx.x;
  const int lane = tid & 63;
  const int wid  = tid >> 6;
  const int wm   = wid >> 2, wn = wid & 3;
  const int lr   = lane & 15, lk = lane >> 4;

  // XCD-aware chunked swizzle (kept: FETCH 1.1GB -> 427MB).
  const int wg = blockIdx.x;
  const int x8 = wg & 7;
  const int lc = wg >> 3;
  const int bc = (x8 & 3) * 8 + (lc & 7);             // h-col tile 0..31
  const int rb = ((x8 >> 2) * 16 + (lc >> 3)) * 256;  // batch row base

  // Staging source offsets (elements). Lane l covers row (l>>2) of its
  // 16-row group, chunk l&3; pre-swizzled source chunk = (l&3)^((l>>3)&3).
  const int srow = lane >> 2;
  const int sc8  = ((lane & 3) ^ ((lane >> 3) & 3)) * 8;
  unsigned int aOff[2], bOff[2];
#pragma unroll
  for (int g = 0; g < 2; ++g) {
    const int arow = rb + wid * 32 + g * 16 + srow;
    aOff[g] = (unsigned)arow * 2048u + (unsigned)sc8;
    const int c  = wid * 32 + g * 16 + srow;            // block-col index
    const int cf = c >> 4, ce = c & 15;
    const int gate = (cf & 1) | ((cf >> 2) & 2);
    const int hch  = (cf >> 1) & 3;
    const int brow = gate * 2048 + bc * 64 + hch * 16 + ce;
    bOff[g] = (unsigned)brow * 2048u + (unsigned)sc8;
  }

  // Precomputed per-lane LDS read bases; offsets are compile-time.
  // A byte: [buf]*32768 + row*64 + phys*16, row = QM*128+wm*64+mr*16+lr.
  // B byte: [buf]*32768 + 16384 + rowB*64 + phys*16, rowB = (QN*8+wn*2+nc)*16+lr.
  // phys = lk ^ ((row>>1)&3) = lk ^ ((lr>>1)&3)  (loop-invariant).
  const int rchunk = lk ^ ((lr >> 1) & 3);
  const char* pA[2];
  const char* pB[2];
#pragma unroll
  for (int p = 0; p < 2; ++p) {
    pA[p] = smc + p * 32768 + wm * 4096 + lr * 64 + rchunk * 16;
    pB[p] = smc + p * 32768 + 16384 + wn * 2048 + lr * 64 + rchunk * 16;
  }

  floatx4 acc[2][4][2][2];
#pragma unroll
  for (int a = 0; a < 2; ++a)
#pragma unroll
    for (int b = 0; b < 4; ++b)
#pragma unroll
      for (int c = 0; c < 2; ++c)
#pragma unroll
        for (int d = 0; d < 2; ++d)
          acc[a][b][c][d] = (floatx4){0.f, 0.f, 0.f, 0.f};

// Stage tile ts (K-rows [ts*32, ts*32+32)): A and B, 2 gloads each.
// Dest is wave-uniform; HW adds lane*16 (linear rows, pre-swizzled source).
#define STAGE_A(ts) {                                                         \
    const int p_ = (ts) & 1;                                                  \
    const unsigned short* s_ = (((ts) < 64) ? xb : hb) + (((ts) & 63) * 32);  \
    gload_lds16(s_ + aOff[0], smc + p_ * 32768 + wid * 2048);                 \
    gload_lds16(s_ + aOff[1], smc + p_ * 32768 + wid * 2048 + 1024); }
#define STAGE_B(ts) {                                                         \
    const int p_ = (ts) & 1;                                                  \
    const unsigned short* s_ = (((ts) < 64) ? wih : whh) + (((ts) & 63) * 32);\
    gload_lds16(s_ + bOff[0], smc + p_ * 32768 + 16384 + wid * 2048);         \
    gload_lds16(s_ + bOff[1], smc + p_ * 32768 + 16384 + wid * 2048 + 1024); }

#define LDAQ(D, P, QM)                                                        \
  _Pragma("unroll") for (int mr = 0; mr < 4; ++mr)                            \
    D[mr] = *(const bf16x8*)(pA[P] + ((QM) * 8192 + mr * 1024));
#define LDBQ(D, P, QN)                                                        \
  _Pragma("unroll") for (int nc = 0; nc < 2; ++nc)                            \
    D[nc] = *(const bf16x8*)(pB[P] + ((QN) * 8192 + nc * 1024));
#define MFMA8(QM, QN, AF, BF)                                                 \
  __builtin_amdgcn_s_setprio(1);                                              \
  _Pragma("unroll") for (int mr = 0; mr < 4; ++mr)                            \
    _Pragma("unroll") for (int nc = 0; nc < 2; ++nc)                          \
      acc[QM][mr][QN][nc] = __builtin_amdgcn_mfma_f32_16x16x32_bf16(          \
          AF[mr], BF[nc], acc[QM][mr][QN][nc], 0, 0, 0);                      \
  __builtin_amdgcn_s_setprio(0);
#define BAR  asm volatile("s_barrier" ::: "memory")
#define VM0  asm volatile("s_waitcnt vmcnt(0)" ::: "memory")
#define NOP  (void)0

// One K-tile(32), ring (0,0)(1,0)(1,1)(0,1), 2 barriers.
// Reads: ph1 A0(4)+B0(2); ph2 A1(4); ph3 B1(2); ph4 none.
// Stages: ph1 A(t+1), ph2 B(t+1) -> ph4 drains exactly those 4 (vmcnt(0)).
// WAR: buf p^1's last reads were tile t-1's, lgkm-consumed before t-1's
// final BAR; stages here come after it. RAW: tile t's buf p staged during
// t-1, vmcnt-confirmed + BAR'd at t-1 ph4.
#define KTILE(P, SA, SB, W) {                                                 \
    bf16x8 a0[4], a1[4], b0[2], b1[2];                                        \
    LDAQ(a0, P, 0); LDBQ(b0, P, 0); SA;                                       \
    MFMA8(0, 0, a0, b0);                                                      \
    LDAQ(a1, P, 1); SB;                                                       \
    MFMA8(1, 0, a1, b0); BAR;                                                 \
    LDBQ(b1, P, 1);                                                           \
    MFMA8(1, 1, a1, b1);                                                      \
    MFMA8(0, 1, a0, b1); W; BAR;                                              \
  }

  // Prologue: stage tile 0, drain, barrier.
  STAGE_A(0); STAGE_B(0);
  VM0;
  BAR;

  // 128 K-tiles of 32 (64 from x/W_ih, 64 from h/W_hh), unrolled x2.
  for (int u = 0; u < 63; ++u) {
    const int t0 = 2 * u;
    KTILE(0, STAGE_A(t0 + 1), STAGE_B(t0 + 1), VM0);
    KTILE(1, STAGE_A(t0 + 2), STAGE_B(t0 + 2), VM0);
  }
  KTILE(0, STAGE_A(127), STAGE_B(127), VM0);  // t = 126
  KTILE(1, NOP, NOP, NOP);                    // t = 127

  // Epilogue: lane-local LSTM (all 4 gates live in-lane).
  const int hcol = bc * 64 + wn * 16 + lr;
  const float b_i = bias[hcol];
  const float b_f = bias[2048 + hcol];
  const float b_j = bias[4096 + hcol];
  const float b_o = bias[6144 + hcol];
#pragma unroll
  for (int qm = 0; qm < 2; ++qm)
#pragma unroll
    for (int mr = 0; mr < 4; ++mr)
#pragma unroll
      for (int r = 0; r < 4; ++r) {
        const int row = rb + qm * 128 + wm * 64 + mr * 16 + lk * 4 + r;
        const float gi = acc[qm][mr][0][0][r] + b_i;
        const float gf = acc[qm][mr][0][1][r] + b_f;
        const float gj = acc[qm][mr][1][0][r] + b_j;
        const float go = acc[qm][mr][1][1][r] + b_o;
        const float iv = sigm(gi);
        const float fv = sigm(gf);
        const float jv = tanh_fast(gj);
        const float ov = sigm(go);
        const size_t idx = (size_t)row * 2048 + hcol;
        const float cp = c_prev[idx];
        const float cv = fv * cp + fminf(1.0f - fv, iv) * jv;
        out_h[idx] = ov * tanh_fast(cv);
        out_c[idx] = cv;
      }
}

extern "C" void kernel_launch(void* const* d_in, const int* in_sizes, int n_in,
                              void* d_out, int out_size, void* d_ws, size_t ws_size,
                              hipStream_t stream) {
  const float* x      = (const float*)d_in[0];
  const float* h_prev = (const float*)d_in[1];
  const float* c_prev = (const float*)d_in[2];
  const float* w_ih   = (const float*)d_in[3];
  const float* w_hh   = (const float*)d_in[4];
  const float* bias   = (const float*)d_in[5];

  float* out_h = (float*)d_out;
  float* out_c = out_h + (size_t)Bsz * Hd;
  unsigned short* wsb = (unsigned short*)d_ws;

  dim3 cgrid(2048, 4);
  cvt4<<<cgrid, 256, 0, stream>>>(x, h_prev, w_ih, w_hh, wsb);

  lstm_gemm<<<1024, 512, 0, stream>>>(wsb, bias, c_prev, out_h, out_c);
}

// Round 13
// 761.529 us; speedup vs baseline: 7.1860x; 7.1860x over previous
//
#include <hip/hip_runtime.h>

#define DEVI __device__ __forceinline__

typedef __attribute__((ext_vector_type(8))) __bf16 bf16x8;
typedef __attribute__((ext_vector_type(16))) float floatx16;

constexpr int Bsz = 8192;   // batch
constexpr int Hd  = 2048;   // hidden
constexpr int INd = 2048;   // input dim
constexpr int N1  = Bsz * INd;

DEVI unsigned short f2bf_rne(float f) {
  unsigned int u = __float_as_uint(f);
  u += 0x7FFFu + ((u >> 16) & 1u);
  return (unsigned short)(u >> 16);
}

__global__ void cvt4(const float* __restrict__ s0, const float* __restrict__ s1,
                     const float* __restrict__ s2, const float* __restrict__ s3,
                     unsigned short* __restrict__ dst) {
  const float* src = (blockIdx.y == 0) ? s0 : (blockIdx.y == 1) ? s1
                   : (blockIdx.y == 2) ? s2 : s3;
  unsigned short* out = dst + (size_t)blockIdx.y * N1;
  const int nv = N1 / 4;
  for (int i = blockIdx.x * blockDim.x + threadIdx.x; i < nv;
       i += gridDim.x * blockDim.x) {
    float4 v = ((const float4*)src)[i];
    ushort4 o;
    o.x = f2bf_rne(v.x); o.y = f2bf_rne(v.y);
    o.z = f2bf_rne(v.z); o.w = f2bf_rne(v.w);
    ((ushort4*)out)[i] = o;
  }
}

DEVI void gload_lds16(const void* g, void* l) {
  __builtin_amdgcn_global_load_lds(
      (const __attribute__((address_space(1))) void*)g,
      (__attribute__((address_space(3))) void*)l, 16, 0, 0);
}

DEVI float sigm(float x) { return 1.0f / (1.0f + __expf(-x)); }
DEVI float tanh_fast(float x) { return 1.0f - 2.0f / (1.0f + __expf(2.0f * x)); }

// R13: 256(batch) x 256(weight) tile, BK=64, 8 waves (2 weight-M "ww" x
// 4 batch-N "wb"), 32x32x16 MFMA (2495 TF ceiling vs 2075 for 16x16),
// TRANSPOSED mfma(W,X) -> gate = reg>>2, float4 epilogue (R5-verified math).
// COLUMN-MAJOR LDS (16B chunks): addr = k8*4096 + row*16. A 32-lane b128
// fragment read = 512 consecutive bytes = 0 bank conflicts by construction;
// staging fills one (k8=wid, 64-row) strip per gload (linear dest, per-lane
// row in source). R11 schedule: 2 barriers/K-tile, 24 reads/wave/K-tile,
// precomputed bases + compile-time offsets, counted vmcnt(4), XCD chunking.
__global__ __launch_bounds__(512, 2) void lstm_gemm(
    const unsigned short* __restrict__ ws,
    const float* __restrict__ bias,
    const float* __restrict__ c_prev,
    float* __restrict__ out_h,
    float* __restrict__ out_c) {
  __shared__ __align__(16) unsigned short sm[2 * 2 * 256 * 64];  // 128 KiB
  char* smc = (char*)sm;

  const unsigned short* xb  = ws;
  const unsigned short* hb  = ws + (size_t)N1;
  const unsigned short* wih = ws + (size_t)2 * N1;
  const unsigned short* whh = ws + (size_t)3 * N1;

  const int tid  = threadIdx.x;
  const int lane = tid & 63;
  const int wid  = tid >> 6;
  const int ww   = wid >> 2;    // weight-M wave 0..1
  const int wb   = wid & 3;     // batch-N wave 0..3
  const int l31  = lane & 31, l5 = lane >> 5;

  // XCD-aware chunked swizzle (FETCH 1.1GB -> 427MB).
  const int wg = blockIdx.x;
  const int x8 = wg & 7;
  const int lc = wg >> 3;
  const int bc = (x8 & 3) * 8 + (lc & 7);             // h-col tile 0..31
  const int rb = ((x8 >> 2) * 16 + (lc >> 3)) * 256;  // batch row base

  // Staging source offsets (elements). gload j fills LDS rows j*64+lane of
  // column k8 = wid. A source row = rb + j*64 + lane; B source row decodes
  // LDS row wr -> weight row gate*2048 + bc*64 + grp*8 + (wr&7),
  // gate=(wr>>3)&3, grp=wr>>5  (R5-verified mapping).
  unsigned int aOff[4], bOff[4];
#pragma unroll
  for (int j = 0; j < 4; ++j) {
    const int arow = rb + j * 64 + lane;
    aOff[j] = (unsigned)arow * 2048u + (unsigned)(wid * 8);
    const int wr = j * 64 + lane;
    const int wrow = ((wr >> 3) & 3) * 2048 + bc * 64 + (wr >> 5) * 8 + (wr & 7);
    bOff[j] = (unsigned)wrow * 2048u + (unsigned)(wid * 8);
  }

  // Precomputed per-lane LDS read bases (column-major; loop-invariant).
  // X (batch) in A-half (+0), W in B-half (+32768), buffer stride 65536.
  // Frag chunk k8 = ks*2 + l5 -> base includes l5*4096; ks adds 8192.
  const char* pX[2];
  const char* pW[2];
#pragma unroll
  for (int p = 0; p < 2; ++p) {
    pX[p] = smc + p * 65536 + wb * 512 + l31 * 16 + l5 * 4096;
    pW[p] = smc + p * 65536 + 32768 + ww * 1024 + l31 * 16 + l5 * 4096;
  }

  floatx16 acc[2][2][2];  // [qw][mrw][qb]
#pragma unroll
  for (int a = 0; a < 2; ++a)
#pragma unroll
    for (int b = 0; b < 2; ++b)
#pragma unroll
      for (int c = 0; c < 2; ++c)
#pragma unroll
        for (int e = 0; e < 16; ++e) acc[a][b][c][e] = 0.f;

// Stage half h of tile ts: rows [2h*64, 2h*64+128) of column k8=wid.
#define STAGE_A(ts, h) {                                                      \
    const int p_ = (ts) & 1;                                                  \
    const unsigned short* s_ = (((ts) < 32) ? xb : hb) + (((ts) & 31) * 64);  \
    gload_lds16(s_ + aOff[2 * (h)],     smc + p_ * 65536 + wid * 4096 + (2 * (h)) * 1024);     \
    gload_lds16(s_ + aOff[2 * (h) + 1], smc + p_ * 65536 + wid * 4096 + (2 * (h) + 1) * 1024); }
#define STAGE_B(ts, h) {                                                      \
    const int p_ = (ts) & 1;                                                  \
    const unsigned short* s_ = (((ts) < 32) ? wih : whh) + (((ts) & 31) * 64);\
    gload_lds16(s_ + bOff[2 * (h)],     smc + p_ * 65536 + 32768 + wid * 4096 + (2 * (h)) * 1024);     \
    gload_lds16(s_ + bOff[2 * (h) + 1], smc + p_ * 65536 + 32768 + wid * 4096 + (2 * (h) + 1) * 1024); }

// Fragment reads: base + compile-time offset only (ds offset <= 27.1 KB).
#define LDW(D, P, QW)                                                         \
  _Pragma("unroll") for (int mrw = 0; mrw < 2; ++mrw)                         \
    _Pragma("unroll") for (int ks = 0; ks < 4; ++ks)                          \
      D[mrw][ks] = *(const bf16x8*)(pW[P] + ((QW) * 2048 + mrw * 512 + ks * 8192));
#define LDX(D, P, QB)                                                         \
  _Pragma("unroll") for (int ks = 0; ks < 4; ++ks)                            \
      D[ks] = *(const bf16x8*)(pX[P] + ((QB) * 2048 + ks * 8192));
#define MM(QW, QB, WF, XF)                                                    \
  __builtin_amdgcn_s_setprio(1);                                              \
  _Pragma("unroll") for (int mrw = 0; mrw < 2; ++mrw)                         \
    _Pragma("unroll") for (int ks = 0; ks < 4; ++ks)                          \
      acc[QW][mrw][QB] = __builtin_amdgcn_mfma_f32_32x32x16_bf16(             \
          WF[mrw][ks], XF[ks], acc[QW][mrw][QB], 0, 0, 0);                    \
  __builtin_amdgcn_s_setprio(0);
#define BAR  asm volatile("s_barrier" ::: "memory")
#define VM4  asm volatile("s_waitcnt vmcnt(4)" ::: "memory")
#define VM0  asm volatile("s_waitcnt vmcnt(0)" ::: "memory")
#define NOP  (void)0

// R11 schedule, ring (qw,qb) = (0,0)(1,0)(1,1)(0,1), 2 barriers/K-tile.
// Reads: ph1 W0(8)+X0(4); ph2 W1(8); ph3 X1(4); ph4 none (full holds).
// Stages (R11 ledger): ph1 A(t+1,0); ph2 B(t+1,1); ph3 B(t+2,0), A(t+2,1);
// ph4 VM4 (leaves newest 4 = the t+2 pair) then BAR.
#define KTILE(P, S1, S2a, S2b, S3, W4) {                                      \
    bf16x8 w0[2][4], w1[2][4], x0[4], x1[4];                                  \
    LDW(w0, P, 0); LDX(x0, P, 0); S1;                                         \
    MM(0, 0, w0, x0);                                                         \
    LDW(w1, P, 1); S2a;                                                       \
    MM(1, 0, w1, x0); BAR;                                                    \
    LDX(x1, P, 1); S2b; S3;                                                   \
    MM(1, 1, w1, x1);                                                         \
    MM(0, 1, w0, x1); W4; BAR;                                                \
  }

  // Prologue: tile 0 complete + tile 1's (B h0, A h1); full drain once.
  STAGE_A(0, 0); STAGE_B(0, 0); STAGE_A(0, 1); STAGE_B(0, 1);
  STAGE_B(1, 0); STAGE_A(1, 1);
  VM0;
  BAR;

  for (int u = 0; u < 31; ++u) {
    const int t0 = 2 * u;
    KTILE(0, STAGE_A(t0 + 1, 0), STAGE_B(t0 + 1, 1),
          STAGE_B(t0 + 2, 0), STAGE_A(t0 + 2, 1), VM4);
    KTILE(1, STAGE_A(t0 + 2, 0), STAGE_B(t0 + 2, 1),
          STAGE_B(t0 + 3, 0), STAGE_A(t0 + 3, 1), VM4);
  }
  KTILE(0, STAGE_A(63, 0), STAGE_B(63, 1), NOP, NOP, VM0);  // t = 62
  KTILE(1, NOP, NOP, NOP, NOP, NOP);                        // t = 63

  // Epilogue (R5-verified): gate = reg>>2 lane-local, float4 ld/st.
#pragma unroll
  for (int qw = 0; qw < 2; ++qw)
#pragma unroll
    for (int mrw = 0; mrw < 2; ++mrw) {
      const int hb4 = bc * 64 + (qw * 4 + ww * 2 + mrw) * 8 + l5 * 4;
      const float4 bi4 = *(const float4*)&bias[hb4];
      const float4 bf4 = *(const float4*)&bias[2048 + hb4];
      const float4 bj4 = *(const float4*)&bias[4096 + hb4];
      const float4 bo4 = *(const float4*)&bias[6144 + hb4];
#pragma unroll
      for (int qb = 0; qb < 2; ++qb) {
        const int brow = rb + qb * 128 + wb * 32 + l31;
        const size_t base = (size_t)brow * 2048 + hb4;
        const float4 cp = *(const float4*)&c_prev[base];
        float4 hv, cv;
#pragma unroll
        for (int q = 0; q < 4; ++q) {
          const float gi = acc[qw][mrw][qb][q]      + ((const float*)&bi4)[q];
          const float gf = acc[qw][mrw][qb][4 + q]  + ((const float*)&bf4)[q];
          const float gj = acc[qw][mrw][qb][8 + q]  + ((const float*)&bj4)[q];
          const float go = acc[qw][mrw][qb][12 + q] + ((const float*)&bo4)[q];
          const float iv = sigm(gi);
          const float fv = sigm(gf);
          const float jv = tanh_fast(gj);
          const float ov = sigm(go);
          const float cq = fv * ((const float*)&cp)[q] + fminf(1.0f - fv, iv) * jv;
          ((float*)&cv)[q] = cq;
          ((float*)&hv)[q] = ov * tanh_fast(cq);
        }
        *(float4*)&out_h[base] = hv;
        *(float4*)&out_c[base] = cv;
      }
    }
}

extern "C" void kernel_launch(void* const* d_in, const int* in_sizes, int n_in,
                              void* d_out, int out_size, void* d_ws, size_t ws_size,
                              hipStream_t stream) {
  const float* x      = (const float*)d_in[0];
  const float* h_prev = (const float*)d_in[1];
  const float* c_prev = (const float*)d_in[2];
  const float* w_ih   = (const float*)d_in[3];
  const float* w_hh   = (const float*)d_in[4];
  const float* bias   = (const float*)d_in[5];

  float* out_h = (float*)d_out;
  float* out_c = out_h + (size_t)Bsz * Hd;
  unsigned short* wsb = (unsigned short*)d_ws;

  dim3 cgrid(2048, 4);
  cvt4<<<cgrid, 256, 0, stream>>>(x, h_prev, w_ih, w_hh, wsb);

  lstm_gemm<<<1024, 512, 0, stream>>>(wsb, bias, c_prev, out_h, out_c);
}

// Round 14
// 648.713 us; speedup vs baseline: 8.4357x; 1.1739x over previous
//
#include <hip/hip_runtime.h>

#define DEVI __device__ __forceinline__

typedef __attribute__((ext_vector_type(8))) __bf16 bf16x8;
typedef __attribute__((ext_vector_type(4))) float floatx4;

constexpr int Bsz = 8192;   // batch
constexpr int Hd  = 2048;   // hidden
constexpr int INd = 2048;   // input dim
constexpr int N1  = Bsz * INd;

DEVI unsigned short f2bf_rne(float f) {
  unsigned int u = __float_as_uint(f);
  u += 0x7FFFu + ((u >> 16) & 1u);
  return (unsigned short)(u >> 16);
}

__global__ void cvt4(const float* __restrict__ s0, const float* __restrict__ s1,
                     const float* __restrict__ s2, const float* __restrict__ s3,
                     unsigned short* __restrict__ dst) {
  const float* src = (blockIdx.y == 0) ? s0 : (blockIdx.y == 1) ? s1
                   : (blockIdx.y == 2) ? s2 : s3;
  unsigned short* out = dst + (size_t)blockIdx.y * N1;
  const int nv = N1 / 4;
  for (int i = blockIdx.x * blockDim.x + threadIdx.x; i < nv;
       i += gridDim.x * blockDim.x) {
    float4 v = ((const float4*)src)[i];
    ushort4 o;
    o.x = f2bf_rne(v.x); o.y = f2bf_rne(v.y);
    o.z = f2bf_rne(v.z); o.w = f2bf_rne(v.w);
    ((ushort4*)out)[i] = o;
  }
}

DEVI void gload_lds16(const void* g, void* l) {
  __builtin_amdgcn_global_load_lds(
      (const __attribute__((address_space(1))) void*)g,
      (__attribute__((address_space(3))) void*)l, 16, 0, 0);
}

DEVI float sigm(float x) { return 1.0f / (1.0f + __expf(-x)); }
DEVI float tanh_fast(float x) { return 1.0f - 2.0f / (1.0f + __expf(2.0f * x)); }

// R14: 128(batch) x 128(4 gates x 32 h-cols) tile, BK=64, 8 waves (4M x 2N,
// wave sub-tile 32 rows x 64 cols = 4 gate-frags x 16 hcols -> gate = ni,
// lane-local epilogue). 16x16x32 MFMA. LDS = 2buf x (A[128][64]+B[128][64])
// bf16 = 64 KiB -> 2 BLOCKS/CU (4 waves/SIMD): cross-block TLP covers
// barriers/waits (R11's 1-block structure idled the SIMD at each sync).
// VGPR budget: acc 32 + frags 48 + addr ~25 ~= 105 < 128 (launch_bounds 4).
// R11-verified pieces: 8-row XOR chunk swizzle (pre-swizzled global source,
// read phys=(s*4+lk)^(lr&7), conflict-free), precomputed LDS bases +
// compile-time offsets, 2-barrier ring, XCD chunking. Depth-1 dbuf: tile t
// stages ALL of t+1 into buffer p^1 (WAR: p^1's last reads ended before
// t-1's end-BAR); vmcnt(0) at ph4 + end-BAR = RAW for t+1.
__global__ __launch_bounds__(512, 4) void lstm_gemm(
    const unsigned short* __restrict__ ws,
    const float* __restrict__ bias,
    const float* __restrict__ c_prev,
    float* __restrict__ out_h,
    float* __restrict__ out_c) {
  __shared__ __align__(16) unsigned short sm[2 * 2 * 128 * 64];  // 64 KiB
  char* smc = (char*)sm;

  const unsigned short* xb  = ws;
  const unsigned short* hb  = ws + (size_t)N1;
  const unsigned short* wih = ws + (size_t)2 * N1;
  const unsigned short* whh = ws + (size_t)3 * N1;

  const int tid  = threadIdx.x;
  const int lane = tid & 63;
  const int wid  = tid >> 6;
  const int wm   = wid >> 1;    // M wave 0..3 (32 rows each)
  const int wn   = wid & 1;     // N wave 0..1 (64 cols each)
  const int lr   = lane & 15, lk = lane >> 4;

  // XCD-aware chunked swizzle: 4096 blocks = 8 XCDs x 512.
  const int wg = blockIdx.x;
  const int x8 = wg & 7;
  const int lc = wg >> 3;                               // 0..511
  const int bc = (x8 & 3) * 16 + (lc & 15);             // h-col tile 0..63 (32 cols)
  const int rb = ((x8 >> 2) * 32 + (lc >> 4)) * 128;    // batch row base

  // Staging source offsets (elements). Wave wid stages LDS rows
  // [wid*16, wid*16+16) as two 8-row gloads; lane l -> row +(l>>3),
  // pre-swizzled source chunk (l&7)^((l>>3)&7).
  const int srow = lane >> 3;
  const int sc8  = ((lane & 7) ^ (srow & 7)) * 8;
  unsigned int aOff[2], bOff[2];
#pragma unroll
  for (int j = 0; j < 2; ++j) {
    const int r = wid * 16 + j * 8 + srow;       // LDS row 0..127
    aOff[j] = (unsigned)(rb + r) * 2048u + (unsigned)sc8;
    // B LDS row r -> weight row: ni=(r>>4)&3 (gate), wn16=r>>6, ce=r&15.
    const int wrow = ((r >> 4) & 3) * 2048 + bc * 32 + (r >> 6) * 16 + (r & 15);
    bOff[j] = (unsigned)wrow * 2048u + (unsigned)sc8;
  }

  // Precomputed per-lane LDS read bases (A rows: wm*32+mf*16+lr;
  // B rows: wn*64+ni*16+lr; both have row&7 == lr&7).
  const char* pA[2][2];  // [buf][s]
  const char* pB[2][2];
#pragma unroll
  for (int p = 0; p < 2; ++p)
#pragma unroll
    for (int s = 0; s < 2; ++s) {
      const int phys = (s * 4 + lk) ^ (lr & 7);
      pA[p][s] = smc + p * 32768 + wm * 4096 + lr * 128 + phys * 16;
      pB[p][s] = smc + 16384 + p * 32768 + wn * 8192 + lr * 128 + phys * 16;
    }

  floatx4 acc[2][4];  // [mf][ni(gate)]
#pragma unroll
  for (int a = 0; a < 2; ++a)
#pragma unroll
    for (int b = 0; b < 4; ++b)
      acc[a][b] = (floatx4){0.f, 0.f, 0.f, 0.f};

#define STAGE_A(ts) {                                                         \
    const int p_ = (ts) & 1;                                                  \
    const unsigned short* s_ = (((ts) < 32) ? xb : hb) + (((ts) & 31) * 64);  \
    gload_lds16(s_ + aOff[0], smc + p_ * 32768 + wid * 2048);                 \
    gload_lds16(s_ + aOff[1], smc + p_ * 32768 + wid * 2048 + 1024); }
#define STAGE_B(ts) {                                                         \
    const int p_ = (ts) & 1;                                                  \
    const unsigned short* s_ = (((ts) < 32) ? wih : whh) + (((ts) & 31) * 64);\
    gload_lds16(s_ + bOff[0], smc + 16384 + p_ * 32768 + wid * 2048);         \
    gload_lds16(s_ + bOff[1], smc + 16384 + p_ * 32768 + wid * 2048 + 1024); }

// Fragment reads: base + compile-time offset (A: mf*2048; B: ni*2048).
#define LDAm(D, P, MF)                                                        \
  _Pragma("unroll") for (int s = 0; s < 2; ++s)                               \
    D[s] = *(const bf16x8*)(pA[P][s] + ((MF) * 2048));
#define LDBn(D, P, NI)                                                        \
  _Pragma("unroll") for (int s = 0; s < 2; ++s)                               \
    D[s] = *(const bf16x8*)(pB[P][s] + ((NI) * 2048));
// Cluster: one M-frag x two N-frags x two k-slots = 4 MFMA.
#define MM2(MF, AF, BX, NX, BY, NY)                                           \
  __builtin_amdgcn_s_setprio(1);                                              \
  _Pragma("unroll") for (int s = 0; s < 2; ++s) {                             \
    acc[MF][NX] = __builtin_amdgcn_mfma_f32_16x16x32_bf16(                    \
        AF[s], BX[s], acc[MF][NX], 0, 0, 0);                                  \
    acc[MF][NY] = __builtin_amdgcn_mfma_f32_16x16x32_bf16(                    \
        AF[s], BY[s], acc[MF][NY], 0, 0, 0);                                  \
  }                                                                           \
  __builtin_amdgcn_s_setprio(0);
#define BAR  asm volatile("s_barrier" ::: "memory")
#define VM0  asm volatile("s_waitcnt vmcnt(0)" ::: "memory")
#define NOP  (void)0

// One K-tile(64), buf P: 12 reads, 16 MFMA, 2 barriers, stages -> buf P^1.
#define KTILE(P, SA, SB, W) {                                                 \
    bf16x8 a0[2], a1[2], b0[2], b1[2], b2[2], b3[2];                          \
    LDAm(a0, P, 0); LDBn(b0, P, 0); LDBn(b1, P, 1); SA;                       \
    MM2(0, a0, b0, 0, b1, 1);                                                 \
    LDAm(a1, P, 1); SB;                                                       \
    MM2(1, a1, b0, 0, b1, 1); BAR;                                            \
    LDBn(b2, P, 2); LDBn(b3, P, 3);                                           \
    MM2(1, a1, b2, 2, b3, 3);                                                 \
    MM2(0, a0, b2, 2, b3, 3); W; BAR;                                         \
  }

  // Prologue: stage tile 0, drain, barrier.
  STAGE_A(0); STAGE_B(0);
  VM0;
  BAR;

  // 64 K-tiles of 64 (32 from x/W_ih, 32 from h/W_hh), unrolled x2.
  for (int u = 0; u < 31; ++u) {
    const int t0 = 2 * u;
    KTILE(0, STAGE_A(t0 + 1), STAGE_B(t0 + 1), VM0);
    KTILE(1, STAGE_A(t0 + 2), STAGE_B(t0 + 2), VM0);
  }
  KTILE(0, STAGE_A(63), STAGE_B(63), VM0);  // t = 62
  KTILE(1, NOP, NOP, NOP);                  // t = 63

  // Epilogue: gate = ni (lane-local).
  const int hcol = bc * 32 + wn * 16 + lr;
  const float b_i = bias[hcol];
  const float b_f = bias[2048 + hcol];
  const float b_j = bias[4096 + hcol];
  const float b_o = bias[6144 + hcol];
#pragma unroll
  for (int mf = 0; mf < 2; ++mf)
#pragma unroll
    for (int r = 0; r < 4; ++r) {
      const int row = rb + wm * 32 + mf * 16 + lk * 4 + r;
      const float gi = acc[mf][0][r] + b_i;
      const float gf = acc[mf][1][r] + b_f;
      const float gj = acc[mf][2][r] + b_j;
      const float go = acc[mf][3][r] + b_o;
      const float iv = sigm(gi);
      const float fv = sigm(gf);
      const float jv = tanh_fast(gj);
      const float ov = sigm(go);
      const size_t idx = (size_t)row * 2048 + hcol;
      const float cp = c_prev[idx];
      const float cv = fv * cp + fminf(1.0f - fv, iv) * jv;
      out_h[idx] = ov * tanh_fast(cv);
      out_c[idx] = cv;
    }
}

extern "C" void kernel_launch(void* const* d_in, const int* in_sizes, int n_in,
                              void* d_out, int out_size, void* d_ws, size_t ws_size,
                              hipStream_t stream) {
  const float* x      = (const float*)d_in[0];
  const float* h_prev = (const float*)d_in[1];
  const float* c_prev = (const float*)d_in[2];
  const float* w_ih   = (const float*)d_in[3];
  const float* w_hh   = (const float*)d_in[4];
  const float* bias   = (const float*)d_in[5];

  float* out_h = (float*)d_out;
  float* out_c = out_h + (size_t)Bsz * Hd;
  unsigned short* wsb = (unsigned short*)d_ws;

  dim3 cgrid(2048, 4);
  cvt4<<<cgrid, 256, 0, stream>>>(x, h_prev, w_ih, w_hh, wsb);

  // 32 row-panels x 64 col-panels... = (8192/128) x (2048/32) = 64 x 64.
  lstm_gemm<<<4096, 512, 0, stream>>>(wsb, bias, c_prev, out_h, out_c);
}